// Round 5
// baseline (149.042 us; speedup 1.0000x reference)
//
#include <hip/hip_runtime.h>
#include <math.h>

// Problem constants (B=4, S=2048, E=1024, A=64)
#define BATCH 4
#define SLEN  2048
#define EMB   1024
#define AH    64

typedef __attribute__((ext_vector_type(8))) short bf16x8;
typedef __attribute__((ext_vector_type(4))) float f32x4;

#define MFMA16(a, b, c) __builtin_amdgcn_mfma_f32_16x16x32_bf16((a), (b), (c), 0, 0, 0)

__device__ __forceinline__ short f2bf(float x) {  // RNE
  union { float f; unsigned u; } v; v.f = x;
  unsigned r = v.u + 0x7fffu + ((v.u >> 16) & 1u);
  return (short)(r >> 16);
}
__device__ __forceinline__ float bf2f(short h) {
  union { unsigned u; float f; } v; v.u = ((unsigned)(unsigned short)h) << 16;
  return v.f;
}

// Truncate-split 8 fp32 -> bf16 hi (high16) + bf16 lo (trunc of residual).
__device__ __forceinline__ void split_trunc(float4 a0, float4 a1, bf16x8& hi, bf16x8& lo) {
  unsigned c[8] = {__float_as_uint(a0.x), __float_as_uint(a0.y), __float_as_uint(a0.z),
                   __float_as_uint(a0.w), __float_as_uint(a1.x), __float_as_uint(a1.y),
                   __float_as_uint(a1.z), __float_as_uint(a1.w)};
  union { bf16x8 v; unsigned d[4]; } H, L;
  H.d[0] = __builtin_amdgcn_perm(c[1], c[0], 0x07060302u);
  H.d[1] = __builtin_amdgcn_perm(c[3], c[2], 0x07060302u);
  H.d[2] = __builtin_amdgcn_perm(c[5], c[4], 0x07060302u);
  H.d[3] = __builtin_amdgcn_perm(c[7], c[6], 0x07060302u);
  unsigned e[8];
#pragma unroll
  for (int j = 0; j < 8; ++j)
    e[j] = __float_as_uint(__uint_as_float(c[j]) - __uint_as_float(c[j] & 0xffff0000u));
  L.d[0] = __builtin_amdgcn_perm(e[1], e[0], 0x07060302u);
  L.d[1] = __builtin_amdgcn_perm(e[3], e[2], 0x07060302u);
  L.d[2] = __builtin_amdgcn_perm(e[5], e[4], 0x07060302u);
  L.d[3] = __builtin_amdgcn_perm(e[7], e[6], 0x07060302u);
  hi = H.v; lo = L.v;
}

// Triangular chunk-slot offset: off(qt) = sum_{q<qt} (q/2 + 1)
__device__ __forceinline__ int slot_off(int qt) {
  return (qt == 0) ? 0 : qt + (((qt - 1) * (qt - 1)) >> 2);
}

// ---------------------------------------------------------------------------
// Kernel 0: pack Wk [64,1024] fp32 into MFMA B-fragment order, split bf16.
// ---------------------------------------------------------------------------
__global__ __launch_bounds__(256) void prep_wk_kernel(const float* __restrict__ Wk,
                                                      short* __restrict__ Bpk) {
  int tg = blockIdx.x * 256 + threadIdx.x;  // 8192 = 32kc * 4nt * 64lane
  int kc = tg >> 8, rem = tg & 255, nt = rem >> 6, lane = rem & 63;
  int n = nt * 16 + (lane & 15);
  int k = kc * 32 + (lane >> 4) * 8;
  const float* src = Wk + (size_t)n * EMB + k;
  float4 a0 = *(const float4*)src;
  float4 a1 = *(const float4*)(src + 4);
  bf16x8 hi, lo;
  split_trunc(a0, a1, hi, lo);
  short* dst = Bpk + ((size_t)(kc * 4 + nt) * 64 + lane) * 8;
  *(bf16x8*)dst = hi;
  *(bf16x8*)(dst + 65536) = lo;
}

// ---------------------------------------------------------------------------
// Kernel 1: K = emb @ Wk^T via split-bf16 MFMA (hh+hl+lh). 512 blocks.
// Unroll-8 groups: 32 loads issued per group before any consumption -> deep
// memory pipeline against HBM. __launch_bounds__(256,2): VGPR cap 256.
// ---------------------------------------------------------------------------
__global__ __launch_bounds__(256, 2) void gemm_k_kernel(const float* __restrict__ emb,
                                                        const short* __restrict__ Bpk,
                                                        short* __restrict__ Khi,
                                                        short* __restrict__ Klo,
                                                        short* __restrict__ KThi) {
  const int t = threadIdx.x;
  const int l = t & 63, lm = l & 15, quad = l >> 4;
  const int nt = t >> 6;
  const int row0 = blockIdx.x * 16;

  f32x4 acc = {0.f, 0.f, 0.f, 0.f};
  const float* arow = emb + (size_t)(row0 + lm) * EMB + quad * 8;

  for (int kc8 = 0; kc8 < 4; ++kc8) {
    float4 e0[8], e1[8];
    bf16x8 bh[8], bl[8];
#pragma unroll
    for (int u = 0; u < 8; ++u) {
      const int kc = kc8 * 8 + u;
      e0[u] = *(const float4*)(arow + kc * 32);
      e1[u] = *(const float4*)(arow + kc * 32 + 4);
      const short* bp = Bpk + ((size_t)(kc * 4 + nt) * 64 + l) * 8;
      bh[u] = *(const bf16x8*)bp;
      bl[u] = *(const bf16x8*)(bp + 65536);
    }
#pragma unroll
    for (int u = 0; u < 8; ++u) {
      bf16x8 ahi, alo;
      split_trunc(e0[u], e1[u], ahi, alo);
      acc = MFMA16(ahi, bh[u], acc);
      acc = MFMA16(ahi, bl[u], acc);
      acc = MFMA16(alo, bh[u], acc);
    }
  }

  // epilogue: C layout col=lm, row=quad*4+r  (RNE split for K outputs)
  const int b = row0 >> 11, s0 = row0 & 2047;
  short hi4[4];
#pragma unroll
  for (int r = 0; r < 4; ++r) {
    float v = acc[r];
    short h = f2bf(v);
    short lo = f2bf(v - bf2f(h));
    hi4[r] = h;
    size_t idx = (size_t)(row0 + quad * 4 + r) * AH + nt * 16 + lm;
    Khi[idx] = h;
    Klo[idx] = lo;
  }
  size_t kt_idx = ((size_t)b * AH + nt * 16 + lm) * SLEN + s0 + quad * 4;
  *(short4*)&KThi[kt_idx] = make_short4(hi4[0], hi4[1], hi4[2], hi4[3]);
}

// ---------------------------------------------------------------------------
// Kernel 2: flash partials, Bk=128 single-shot. grid (16,32,4) x 256.
// ALL Q+K loads hoisted up-front (36 independent loads in flight), V loads
// issued before softmax so their latency hides under exp/shuffle/LDS.
// __launch_bounds__(256,2): VGPR cap 256 (peak live ~190), 2 waves/SIMD.
// ---------------------------------------------------------------------------
__global__ __launch_bounds__(256, 2) void flash_kernel(const short* __restrict__ Khi,
                                                       const short* __restrict__ Klo,
                                                       const short* __restrict__ KThi,
                                                       short* __restrict__ OpartH,
                                                       float2* __restrict__ mlpart) {
  const int chunk = blockIdx.x, qt = blockIdx.y, b = blockIdx.z;
  if (2 * chunk > qt) return;

  __shared__ short Plds[4][16][136];  // per-wave private
  const int t = threadIdx.x;
  const int w = t >> 6, l = t & 63, lm = l & 15, quad = l >> 4;
  const int qr0 = qt * 64 + w * 16, k0 = chunk * 128;

  // ---- hoist ALL Q and K loads: 36 independent 16B loads fill the pipe ----
  const size_t qbase = ((size_t)b * SLEN + qr0 + lm) * AH + quad * 8;
  const bf16x8 qh0 = *(const bf16x8*)(Khi + qbase);
  const bf16x8 qh1 = *(const bf16x8*)(Khi + qbase + 32);
  const bf16x8 ql0 = *(const bf16x8*)(Klo + qbase);
  const bf16x8 ql1 = *(const bf16x8*)(Klo + qbase + 32);

  bf16x8 kh0[8], kh1[8], kl0[8], kl1[8];
#pragma unroll
  for (int g = 0; g < 8; ++g) {
    const size_t kb = ((size_t)b * SLEN + k0 + g * 16 + lm) * AH + quad * 8;
    kh0[g] = *(const bf16x8*)(Khi + kb);
    kh1[g] = *(const bf16x8*)(Khi + kb + 32);
    kl0[g] = *(const bf16x8*)(Klo + kb);
    kl1[g] = *(const bf16x8*)(Klo + kb + 32);
  }

  // S = Q K^T over 128 keys (8 col-groups of 16)
  f32x4 sc[8];
#pragma unroll
  for (int g = 0; g < 8; ++g) {
    f32x4 s = {0.f, 0.f, 0.f, 0.f};
    s = MFMA16(qh0, kh0[g], s);
    s = MFMA16(qh0, kl0[g], s);
    s = MFMA16(ql0, kh0[g], s);
    s = MFMA16(qh1, kh1[g], s);
    s = MFMA16(qh1, kl1[g], s);
    s = MFMA16(ql1, kh1[g], s);
    sc[g] = s;
  }

  // ---- issue ALL V loads now; latency overlaps softmax + LDS roundtrip ----
  bf16x8 vf[4][4];
#pragma unroll
  for (int kc2 = 0; kc2 < 4; ++kc2)
#pragma unroll
    for (int nt = 0; nt < 4; ++nt)
      vf[kc2][nt] = *(const bf16x8*)(KThi + ((size_t)b * AH + nt * 16 + lm) * SLEN +
                                     k0 + kc2 * 32 + quad * 8);

  // mask + single-pass softmax (C layout: row=quad*4+r, col=g*16+lm)
  float rm[4] = {-INFINITY, -INFINITY, -INFINITY, -INFINITY};
#pragma unroll
  for (int g = 0; g < 8; ++g) {
    const int col = k0 + g * 16 + lm;
#pragma unroll
    for (int r = 0; r < 4; ++r) {
      const int row = qr0 + quad * 4 + r;
      float v = sc[g][r] * 0.125f;
      v = (col > row || v == 0.0f) ? -INFINITY : v;
      sc[g][r] = v;
      rm[r] = fmaxf(rm[r], v);
    }
  }
  float m_i[4], l_i[4];
#pragma unroll
  for (int r = 0; r < 4; ++r) {
    for (int off = 1; off < 16; off <<= 1) rm[r] = fmaxf(rm[r], __shfl_xor(rm[r], off, 16));
    m_i[r] = rm[r];
  }
  float rs[4] = {0.f, 0.f, 0.f, 0.f};
#pragma unroll
  for (int g = 0; g < 8; ++g)
#pragma unroll
    for (int r = 0; r < 4; ++r) {
      float p = (sc[g][r] == -INFINITY) ? 0.f : __expf(sc[g][r] - m_i[r]);
      sc[g][r] = p;
      rs[r] += p;
    }
#pragma unroll
  for (int r = 0; r < 4; ++r) {
    for (int off = 1; off < 16; off <<= 1) rs[r] += __shfl_xor(rs[r], off, 16);
    l_i[r] = rs[r];
  }

  // P -> LDS (C layout -> A-operand layout), per-wave private, no barrier
#pragma unroll
  for (int g = 0; g < 8; ++g)
#pragma unroll
    for (int r = 0; r < 4; ++r)
      Plds[w][quad * 4 + r][g * 16 + lm] = f2bf(sc[g][r]);

  // O = P V over 128 keys
  f32x4 o[4] = {{0.f,0.f,0.f,0.f},{0.f,0.f,0.f,0.f},{0.f,0.f,0.f,0.f},{0.f,0.f,0.f,0.f}};
#pragma unroll
  for (int kc2 = 0; kc2 < 4; ++kc2) {
    bf16x8 pf = *(const bf16x8*)&Plds[w][lm][kc2 * 32 + quad * 8];
#pragma unroll
    for (int nt = 0; nt < 4; ++nt)
      o[nt] = MFMA16(pf, vf[kc2][nt], o[nt]);
  }

  // write partials: bf16 O (contiguous 8 KB/block) + packed (m,l)
  const int slot = b * 272 + slot_off(qt) + chunk;
  short* Ob = OpartH + (size_t)slot * 4096;
#pragma unroll
  for (int nt = 0; nt < 4; ++nt)
#pragma unroll
    for (int r = 0; r < 4; ++r)
      Ob[(size_t)(w * 16 + quad * 4 + r) * AH + nt * 16 + lm] = f2bf(o[nt][r]);
  if (lm == 0) {
#pragma unroll
    for (int r = 0; r < 4; ++r)
      mlpart[(size_t)slot * 64 + w * 16 + quad * 4 + r] = make_float2(m_i[r], l_i[r]);
  }
}

// ---------------------------------------------------------------------------
// Kernel 3: merge, one wave per output row (8192 waves). <=16 chunks/row.
// All chunk loads hoisted (predicated) so they issue together.
// ---------------------------------------------------------------------------
__global__ __launch_bounds__(256, 2) void merge_kernel(const short* __restrict__ OpartH,
                                                       const float2* __restrict__ mlpart,
                                                       float* __restrict__ out) {
  const int t = threadIdx.x, w = t >> 6, l = t & 63;
  const int row = blockIdx.x * 4 + w;
  const int b = row >> 11, s = row & 2047, qt = s >> 6, r = s & 63;
  const int nch = (qt >> 1) + 1;
  const int slotbase = b * 272 + slot_off(qt);

  const int c16 = l & 15;
  float mc = -INFINITY, lc = 0.f;
  if (c16 < nch) {
    float2 ml = mlpart[(size_t)(slotbase + c16) * 64 + r];
    mc = ml.x; lc = ml.y;
  }
  float M = mc;
  for (int off = 1; off < 16; off <<= 1) M = fmaxf(M, __shfl_xor(M, off, 16));
  float wgt = (mc != -INFINITY) ? __expf(mc - M) : 0.f;
  float lw = lc * wgt;
  float L = lw;
  for (int off = 1; off < 16; off <<= 1) L += __shfl_xor(L, off, 16);

  // hoisted, predicated partial loads: all issued before first use
  const size_t obase = (size_t)slotbase * 4096 + (size_t)r * AH + l;
  float vals[16];
#pragma unroll
  for (int c = 0; c < 16; ++c)
    vals[c] = (c < nch) ? bf2f(OpartH[obase + (size_t)c * 4096]) : 0.f;

  float a0 = 0.f, a1 = 0.f, a2 = 0.f, a3 = 0.f;
#pragma unroll
  for (int c = 0; c < 16; c += 4) {
    a0 += __shfl(wgt, c)     * vals[c];
    a1 += __shfl(wgt, c + 1) * vals[c + 1];
    a2 += __shfl(wgt, c + 2) * vals[c + 2];
    a3 += __shfl(wgt, c + 3) * vals[c + 3];
  }
  float acc = (a0 + a1) + (a2 + a3);
  out[(size_t)row * AH + l] = acc / L;
}

// ---------------------------------------------------------------------------
// Workspace (bytes):
//   Bpk     [0,        262144)
//   Khi     [262144,   1310720)
//   Klo     [1310720,  2359296)
//   KThi    [2359296,  3407872)
//   OpartH  [3407872,  12320768)   1088 slots x 4096 bf16 (8.9 MB)
//   mlpart  [12320768, 12877824)   1088 x 64 float2
// ---------------------------------------------------------------------------
extern "C" void kernel_launch(void* const* d_in, const int* in_sizes, int n_in,
                              void* d_out, int out_size, void* d_ws, size_t ws_size,
                              hipStream_t stream) {
  const float* emb = (const float*)d_in[0];
  const float* Wk  = (const float*)d_in[1];
  float* out = (float*)d_out;
  char* ws = (char*)d_ws;

  short*  Bpk    = (short*)(ws);
  short*  Khi    = (short*)(ws + 262144);
  short*  Klo    = (short*)(ws + 1310720);
  short*  KThi   = (short*)(ws + 2359296);
  short*  OpartH = (short*)(ws + 3407872);
  float2* mlpart = (float2*)(ws + 12320768);

  prep_wk_kernel<<<dim3(32), dim3(256), 0, stream>>>(Wk, Bpk);
  gemm_k_kernel<<<dim3(512), dim3(256), 0, stream>>>(emb, Bpk, Khi, Klo, KThi);
  flash_kernel<<<dim3(16, 32, 4), dim3(256), 0, stream>>>(Khi, Klo, KThi, OpartH, mlpart);
  merge_kernel<<<dim3(2048), dim3(256), 0, stream>>>(OpartH, mlpart, out);
}

// Round 6
// 112.655 us; speedup vs baseline: 1.3230x; 1.3230x over previous
//
#include <hip/hip_runtime.h>
#include <math.h>

// Problem constants (B=4, S=2048, E=1024, A=64)
#define BATCH 4
#define SLEN  2048
#define EMB   1024
#define AH    64

typedef __attribute__((ext_vector_type(8))) short bf16x8;
typedef __attribute__((ext_vector_type(4))) float f32x4;

#define MFMA16(a, b, c) __builtin_amdgcn_mfma_f32_16x16x32_bf16((a), (b), (c), 0, 0, 0)

// async 16B global->LDS: zero VGPR cost, guaranteed in-flight batching.
// LDS dest = wave-uniform base + lane*16 (implicit).
__device__ __forceinline__ void async16(const void* g, void* l) {
  __builtin_amdgcn_global_load_lds(
      (const __attribute__((address_space(1))) unsigned int*)g,
      (__attribute__((address_space(3))) unsigned int*)l, 16, 0, 0);
}

__device__ __forceinline__ short f2bf(float x) {  // RNE
  union { float f; unsigned u; } v; v.f = x;
  unsigned r = v.u + 0x7fffu + ((v.u >> 16) & 1u);
  return (short)(r >> 16);
}
__device__ __forceinline__ float bf2f(short h) {
  union { unsigned u; float f; } v; v.u = ((unsigned)(unsigned short)h) << 16;
  return v.f;
}

// Truncate-split 8 fp32 -> bf16 hi (high16) + bf16 lo (trunc of residual).
__device__ __forceinline__ void split_trunc(float4 a0, float4 a1, bf16x8& hi, bf16x8& lo) {
  unsigned c[8] = {__float_as_uint(a0.x), __float_as_uint(a0.y), __float_as_uint(a0.z),
                   __float_as_uint(a0.w), __float_as_uint(a1.x), __float_as_uint(a1.y),
                   __float_as_uint(a1.z), __float_as_uint(a1.w)};
  union { bf16x8 v; unsigned d[4]; } H, L;
  H.d[0] = __builtin_amdgcn_perm(c[1], c[0], 0x07060302u);
  H.d[1] = __builtin_amdgcn_perm(c[3], c[2], 0x07060302u);
  H.d[2] = __builtin_amdgcn_perm(c[5], c[4], 0x07060302u);
  H.d[3] = __builtin_amdgcn_perm(c[7], c[6], 0x07060302u);
  unsigned e[8];
#pragma unroll
  for (int j = 0; j < 8; ++j)
    e[j] = __float_as_uint(__uint_as_float(c[j]) - __uint_as_float(c[j] & 0xffff0000u));
  L.d[0] = __builtin_amdgcn_perm(e[1], e[0], 0x07060302u);
  L.d[1] = __builtin_amdgcn_perm(e[3], e[2], 0x07060302u);
  L.d[2] = __builtin_amdgcn_perm(e[5], e[4], 0x07060302u);
  L.d[3] = __builtin_amdgcn_perm(e[7], e[6], 0x07060302u);
  hi = H.v; lo = L.v;
}

// Triangular chunk-slot offset: off(qt) = sum_{q<qt} (q/2 + 1)
__device__ __forceinline__ int slot_off(int qt) {
  return (qt == 0) ? 0 : qt + (((qt - 1) * (qt - 1)) >> 2);
}

// Kpack chunk layout (shorts), per (b, chunk of 128 keys), 24576 shorts = 48 KB:
//   [0,8192):      KBhi  [kb(8)][h(2)][lane(64)][8]   S-MFMA B-frag, hi plane
//   [8192,16384):  KBlo  same, lo plane
//   [16384,24576): VB    [kc2(4)][nt(4)][lane(64)][8] PV-MFMA B-frag (hi only)
#define CH_SHORTS 24576

// ---------------------------------------------------------------------------
// Kernel 0: pack Wk [64,1024] fp32 -> BpkG [kc(32)][nt(4)][pl(2)][lane(64)][8]
// ---------------------------------------------------------------------------
__global__ __launch_bounds__(256) void prep_wk_kernel(const float* __restrict__ Wk,
                                                      short* __restrict__ BpkG) {
  int tg = blockIdx.x * 256 + threadIdx.x;  // 8192 = 32kc * 4nt * 64lane
  int kc = tg >> 8, rem = tg & 255, nt = rem >> 6, lane = rem & 63;
  int n = nt * 16 + (lane & 15);
  int k = kc * 32 + (lane >> 4) * 8;
  const float* src = Wk + (size_t)n * EMB + k;
  float4 a0 = *(const float4*)src;
  float4 a1 = *(const float4*)(src + 4);
  bf16x8 hi, lo;
  split_trunc(a0, a1, hi, lo);
  short* dst = BpkG + ((size_t)(kc * 4 + nt) * 128 + lane) * 8;  // pl=0
  *(bf16x8*)dst = hi;
  *(bf16x8*)(dst + 512) = lo;  // pl=1
}

// ---------------------------------------------------------------------------
// Kernel 1: K = emb @ Wk^T, m97-style LDS staging via global_load_lds.
// 512 blocks x 256; BM=16, K-loop 8 steps of BK=128.
// LDS: emb tile 16x128 fp32 swizzled (8 KB) + Bpk slice (32 KB) = 40 KB.
// Epilogue scatters split-bf16 K into Kpack fragment layout.
// ---------------------------------------------------------------------------
__global__ __launch_bounds__(256) void gemm_k_kernel(const float* __restrict__ emb,
                                                     const short* __restrict__ BpkG,
                                                     short* __restrict__ Kpack) {
  __shared__ __align__(16) char glds[40960];
  float* embT = (float*)glds;             // [16][128] fp32, 16B-units XOR-swizzled by row
  short* bpkT = (short*)(glds + 8192);    // [kc(4)][nt(4)][pl(2)][lane][8]

  const int t = threadIdx.x;
  const int w = t >> 6, l = t & 63, lm = l & 15, quad = l >> 4;
  const int nt = w;
  const int row0 = blockIdx.x * 16;

  f32x4 acc = {0.f, 0.f, 0.f, 0.f};

  for (int step = 0; step < 8; ++step) {
    __syncthreads();  // previous-step LDS reads complete before overwrite
    // stage emb 16 rows x 128 e (fp32), XOR-swizzled 16B units
#pragma unroll
    for (int u = 0; u < 2; ++u) {
      int rowl = (w * 2 + u) * 2 + (l >> 5);
      int du = (l & 31) ^ (rowl & 7);
      async16(emb + (size_t)(row0 + rowl) * EMB + step * 128 + du * 4,
              embT + (w * 2 + u) * 256);
    }
    // stage Bpk slice: 4 kc x 4 nt x 2 pl x 1 KB = 32 KB
    const short* bg = BpkG + (size_t)step * 16384;
#pragma unroll
    for (int u = 0; u < 8; ++u)
      async16(bg + (w * 8 + u) * 512 + l * 8, bpkT + (w * 8 + u) * 512);
    __syncthreads();  // drains vmcnt(0): all staging visible

#pragma unroll
    for (int kc = 0; kc < 4; ++kc) {
      int du0 = kc * 8 + quad * 2;
      float4 a0 = *(const float4*)((char*)embT + lm * 512 + ((du0) ^ (lm & 7)) * 16);
      float4 a1 = *(const float4*)((char*)embT + lm * 512 + ((du0 + 1) ^ (lm & 7)) * 16);
      bf16x8 ahi, alo;
      split_trunc(a0, a1, ahi, alo);
      bf16x8 bhi = *(const bf16x8*)(bpkT + (((kc * 4 + nt) * 2 + 0) * 64 + l) * 8);
      bf16x8 blo = *(const bf16x8*)(bpkT + (((kc * 4 + nt) * 2 + 1) * 64 + l) * 8);
      acc = MFMA16(ahi, bhi, acc);
      acc = MFMA16(ahi, blo, acc);
      acc = MFMA16(alo, bhi, acc);
    }
  }

  // epilogue: C layout (row=quad*4+r within tile, col a=nt*16+lm) -> Kpack scatter
  const int a = nt * 16 + lm;
#pragma unroll
  for (int r = 0; r < 4; ++r) {
    int srow = row0 + quad * 4 + r;
    float v = acc[r];
    short h = f2bf(v);
    short lo2 = f2bf(v - bf2f(h));
    int bb = srow >> 11, si = srow & 2047, c = si >> 7, key = si & 127;
    int kb = key >> 4, klm = key & 15;
    size_t cb = (size_t)(bb * 16 + c) * CH_SHORTS;
    size_t kbo = (size_t)((kb * 2 + (a >> 5)) * 64 + ((a & 31) >> 3) * 16 + klm) * 8 + (a & 7);
    Kpack[cb + kbo] = h;
    Kpack[cb + 8192 + kbo] = lo2;
    size_t vbo = (size_t)(((key >> 5) * 4 + (a >> 4)) * 64 + ((key & 31) >> 3) * 16 + (a & 15)) * 8 + (key & 7);
    Kpack[cb + 16384 + vbo] = h;
  }
}

// ---------------------------------------------------------------------------
// Kernel 2: flash partials. grid (16 chunks, 32 qt, 4 b) x 256.
// Stage whole 48 KB Kpack chunk via 12 async16/thread -> one barrier ->
// all fragment reads are conflict-free ds_read_b128. Q = 4 direct 16B loads.
// Plds aliases the dead KBhi/KBlo region after a second barrier.
// ---------------------------------------------------------------------------
__global__ __launch_bounds__(256) void flash_kernel(const short* __restrict__ Kpack,
                                                    short* __restrict__ OpartH,
                                                    float2* __restrict__ mlpart) {
  const int chunk = blockIdx.x, qt = blockIdx.y, b = blockIdx.z;
  if (2 * chunk > qt) return;

  __shared__ __align__(16) short KLs[CH_SHORTS];
  const int t = threadIdx.x;
  const int w = t >> 6, l = t & 63, lm = l & 15, quad = l >> 4;
  const int qr0 = qt * 64 + w * 16, k0 = chunk * 128;

  // Q A-frags: 4 direct coalesced 16B loads (uniform + l*16) from Kpack
  const short* qG = Kpack + (size_t)(b * 16 + (qt >> 1)) * CH_SHORTS + ((qt & 1) * 4 + w) * 1024;
  bf16x8 qh0 = *(const bf16x8*)(qG + l * 8);
  bf16x8 qh1 = *(const bf16x8*)(qG + 512 + l * 8);
  bf16x8 ql0 = *(const bf16x8*)(qG + 8192 + l * 8);
  bf16x8 ql1 = *(const bf16x8*)(qG + 8192 + 512 + l * 8);

  // stage the whole 48 KB chunk: 12 async issues per thread, zero VGPR
  const short* chunkG = Kpack + (size_t)(b * 16 + chunk) * CH_SHORTS;
#pragma unroll
  for (int u = 0; u < 12; ++u) {
    int slot = w * 12 + u;  // 48 slots x 1024 B
    async16(chunkG + slot * 512 + l * 8, KLs + slot * 512);
  }
  __syncthreads();  // vmcnt(0) drain: chunk resident in LDS (Q loads also done)

  // S = Q K^T: 8 key-groups x (2 a-chunks) x split(hh+hl+lh)
  f32x4 sc[8];
#pragma unroll
  for (int g = 0; g < 8; ++g) {
    bf16x8 bh0 = *(const bf16x8*)(KLs + ((g * 2 + 0) * 64 + l) * 8);
    bf16x8 bh1 = *(const bf16x8*)(KLs + ((g * 2 + 1) * 64 + l) * 8);
    bf16x8 bl0 = *(const bf16x8*)(KLs + 8192 + ((g * 2 + 0) * 64 + l) * 8);
    bf16x8 bl1 = *(const bf16x8*)(KLs + 8192 + ((g * 2 + 1) * 64 + l) * 8);
    f32x4 s = {0.f, 0.f, 0.f, 0.f};
    s = MFMA16(qh0, bh0, s);
    s = MFMA16(qh0, bl0, s);
    s = MFMA16(ql0, bh0, s);
    s = MFMA16(qh1, bh1, s);
    s = MFMA16(qh1, bl1, s);
    s = MFMA16(ql1, bh1, s);
    sc[g] = s;
  }

  // mask + single-pass softmax (C layout: row=quad*4+r, col=g*16+lm)
  float rm[4] = {-INFINITY, -INFINITY, -INFINITY, -INFINITY};
#pragma unroll
  for (int g = 0; g < 8; ++g) {
    const int col = k0 + g * 16 + lm;
#pragma unroll
    for (int r = 0; r < 4; ++r) {
      const int row = qr0 + quad * 4 + r;
      float v = sc[g][r] * 0.125f;
      v = (col > row || v == 0.0f) ? -INFINITY : v;
      sc[g][r] = v;
      rm[r] = fmaxf(rm[r], v);
    }
  }
  float m_i[4], l_i[4];
#pragma unroll
  for (int r = 0; r < 4; ++r) {
    for (int off = 1; off < 16; off <<= 1) rm[r] = fmaxf(rm[r], __shfl_xor(rm[r], off, 16));
    m_i[r] = rm[r];
  }
  float rs[4] = {0.f, 0.f, 0.f, 0.f};
#pragma unroll
  for (int g = 0; g < 8; ++g)
#pragma unroll
    for (int r = 0; r < 4; ++r) {
      float p = (sc[g][r] == -INFINITY) ? 0.f : __expf(sc[g][r] - m_i[r]);
      sc[g][r] = p;
      rs[r] += p;
    }
#pragma unroll
  for (int r = 0; r < 4; ++r) {
    for (int off = 1; off < 16; off <<= 1) rs[r] += __shfl_xor(rs[r], off, 16);
    l_i[r] = rs[r];
  }

  __syncthreads();  // ALL waves done reading KBhi/KBlo -> safe to alias with Plds

  // P -> Plds (C layout -> A-operand layout), per-wave region in dead KB space
  short* Pw = KLs + w * 2112;  // [16][132] shorts; 4 waves end at 16896 B < 32 KB
#pragma unroll
  for (int g = 0; g < 8; ++g)
#pragma unroll
    for (int r = 0; r < 4; ++r)
      Pw[(quad * 4 + r) * 132 + g * 16 + lm] = f2bf(sc[g][r]);

  // O = P V over 128 keys; V frags from VB region (disjoint from Plds)
  f32x4 o[4] = {{0.f,0.f,0.f,0.f},{0.f,0.f,0.f,0.f},{0.f,0.f,0.f,0.f},{0.f,0.f,0.f,0.f}};
#pragma unroll
  for (int kc2 = 0; kc2 < 4; ++kc2) {
    bf16x8 pf = *(const bf16x8*)(Pw + lm * 132 + kc2 * 32 + quad * 8);
#pragma unroll
    for (int nt = 0; nt < 4; ++nt) {
      bf16x8 vf = *(const bf16x8*)(KLs + 16384 + ((kc2 * 4 + nt) * 64 + l) * 8);
      o[nt] = MFMA16(pf, vf, o[nt]);
    }
  }

  // write partials: bf16 O (contiguous 8 KB/block) + packed (m,l)
  const int slot = b * 272 + slot_off(qt) + chunk;
  short* Ob = OpartH + (size_t)slot * 4096;
#pragma unroll
  for (int nt = 0; nt < 4; ++nt)
#pragma unroll
    for (int r = 0; r < 4; ++r)
      Ob[(size_t)(w * 16 + quad * 4 + r) * AH + nt * 16 + lm] = f2bf(o[nt][r]);
  if (lm == 0) {
#pragma unroll
    for (int r = 0; r < 4; ++r)
      mlpart[(size_t)slot * 64 + w * 16 + quad * 4 + r] = make_float2(m_i[r], l_i[r]);
  }
}

// ---------------------------------------------------------------------------
// Kernel 3: merge, one wave per output row (8192 waves). <=16 chunks/row.
// ---------------------------------------------------------------------------
__global__ __launch_bounds__(256) void merge_kernel(const short* __restrict__ OpartH,
                                                    const float2* __restrict__ mlpart,
                                                    float* __restrict__ out) {
  const int t = threadIdx.x, w = t >> 6, l = t & 63;
  const int row = blockIdx.x * 4 + w;
  const int b = row >> 11, s = row & 2047, qt = s >> 6, r = s & 63;
  const int nch = (qt >> 1) + 1;
  const int slotbase = b * 272 + slot_off(qt);

  const int c16 = l & 15;
  float mc = -INFINITY, lc = 0.f;
  if (c16 < nch) {
    float2 ml = mlpart[(size_t)(slotbase + c16) * 64 + r];
    mc = ml.x; lc = ml.y;
  }
  float M = mc;
  for (int off = 1; off < 16; off <<= 1) M = fmaxf(M, __shfl_xor(M, off, 16));
  float wgt = (mc != -INFINITY) ? __expf(mc - M) : 0.f;
  float lw = lc * wgt;
  float L = lw;
  for (int off = 1; off < 16; off <<= 1) L += __shfl_xor(L, off, 16);

  const size_t obase = (size_t)slotbase * 4096 + (size_t)r * AH + l;
  float vals[16];
#pragma unroll
  for (int c = 0; c < 16; ++c)
    vals[c] = (c < nch) ? bf2f(OpartH[obase + (size_t)c * 4096]) : 0.f;

  float a0 = 0.f, a1 = 0.f, a2 = 0.f, a3 = 0.f;
#pragma unroll
  for (int c = 0; c < 16; c += 4) {
    a0 += __shfl(wgt, c)     * vals[c];
    a1 += __shfl(wgt, c + 1) * vals[c + 1];
    a2 += __shfl(wgt, c + 2) * vals[c + 2];
    a3 += __shfl(wgt, c + 3) * vals[c + 3];
  }
  float acc = (a0 + a1) + (a2 + a3);
  out[(size_t)row * AH + l] = acc / L;
}

// ---------------------------------------------------------------------------
// Workspace (bytes):
//   Kpack   [0,        3145728)    4 b x 16 chunks x 48 KB
//   BpkG    [3145728,  3670016)    512 KB
//   OpartH  [3670016,  12582912)   1088 slots x 4096 bf16
//   mlpart  [12582912, 13139968)   1088 x 64 float2
// ---------------------------------------------------------------------------
extern "C" void kernel_launch(void* const* d_in, const int* in_sizes, int n_in,
                              void* d_out, int out_size, void* d_ws, size_t ws_size,
                              hipStream_t stream) {
  const float* emb = (const float*)d_in[0];
  const float* Wk  = (const float*)d_in[1];
  float* out = (float*)d_out;
  char* ws = (char*)d_ws;

  short*  Kpack  = (short*)(ws);
  short*  BpkG   = (short*)(ws + 3145728);
  short*  OpartH = (short*)(ws + 3670016);
  float2* mlpart = (float2*)(ws + 12582912);

  prep_wk_kernel<<<dim3(32), dim3(256), 0, stream>>>(Wk, BpkG);
  gemm_k_kernel<<<dim3(512), dim3(256), 0, stream>>>(emb, BpkG, Kpack);
  flash_kernel<<<dim3(16, 32, 4), dim3(256), 0, stream>>>(Kpack, OpartH, mlpart);
  merge_kernel<<<dim3(2048), dim3(256), 0, stream>>>(OpartH, mlpart, out);
}

// Round 7
// 109.341 us; speedup vs baseline: 1.3631x; 1.0303x over previous
//
#include <hip/hip_runtime.h>
#include <math.h>

// Problem constants (B=4, S=2048, E=1024, A=64)
#define BATCH 4
#define SLEN  2048
#define EMB   1024
#define AH    64

typedef __attribute__((ext_vector_type(8))) short bf16x8;
typedef __attribute__((ext_vector_type(4))) float f32x4;

#define MFMA16(a, b, c) __builtin_amdgcn_mfma_f32_16x16x32_bf16((a), (b), (c), 0, 0, 0)

// async 16B global->LDS: zero VGPR cost, guaranteed in-flight batching.
// LDS dest = wave-uniform base + lane*16 (implicit).
__device__ __forceinline__ void async16(const void* g, void* l) {
  __builtin_amdgcn_global_load_lds(
      (const __attribute__((address_space(1))) unsigned int*)g,
      (__attribute__((address_space(3))) unsigned int*)l, 16, 0, 0);
}

__device__ __forceinline__ short f2bf(float x) {  // RNE
  union { float f; unsigned u; } v; v.f = x;
  unsigned r = v.u + 0x7fffu + ((v.u >> 16) & 1u);
  return (short)(r >> 16);
}
__device__ __forceinline__ float bf2f(short h) {
  union { unsigned u; float f; } v; v.u = ((unsigned)(unsigned short)h) << 16;
  return v.f;
}

// Truncate-split 8 fp32 -> bf16 hi (high16) + bf16 lo (trunc of residual).
__device__ __forceinline__ void split_trunc(float4 a0, float4 a1, bf16x8& hi, bf16x8& lo) {
  unsigned c[8] = {__float_as_uint(a0.x), __float_as_uint(a0.y), __float_as_uint(a0.z),
                   __float_as_uint(a0.w), __float_as_uint(a1.x), __float_as_uint(a1.y),
                   __float_as_uint(a1.z), __float_as_uint(a1.w)};
  union { bf16x8 v; unsigned d[4]; } H, L;
  H.d[0] = __builtin_amdgcn_perm(c[1], c[0], 0x07060302u);
  H.d[1] = __builtin_amdgcn_perm(c[3], c[2], 0x07060302u);
  H.d[2] = __builtin_amdgcn_perm(c[5], c[4], 0x07060302u);
  H.d[3] = __builtin_amdgcn_perm(c[7], c[6], 0x07060302u);
  unsigned e[8];
#pragma unroll
  for (int j = 0; j < 8; ++j)
    e[j] = __float_as_uint(__uint_as_float(c[j]) - __uint_as_float(c[j] & 0xffff0000u));
  L.d[0] = __builtin_amdgcn_perm(e[1], e[0], 0x07060302u);
  L.d[1] = __builtin_amdgcn_perm(e[3], e[2], 0x07060302u);
  L.d[2] = __builtin_amdgcn_perm(e[5], e[4], 0x07060302u);
  L.d[3] = __builtin_amdgcn_perm(e[7], e[6], 0x07060302u);
  hi = H.v; lo = L.v;
}

// Triangular chunk-slot offset: off(qt) = sum_{q<qt} (q/2 + 1)
__device__ __forceinline__ int slot_off(int qt) {
  return (qt == 0) ? 0 : qt + (((qt - 1) * (qt - 1)) >> 2);
}

// Kpack chunk layout (shorts), per (b, chunk of 128 keys), 24576 shorts = 48 KB:
//   [0,8192):      KBhi  [kb(8)][a32(2)][lane(64)][8]   S-MFMA B-frag, hi plane
//   [8192,16384):  KBlo  same, lo plane
//   [16384,24576): VB    [kc2(4)][nt(4)][lane(64)][8] PV-MFMA B-frag (hi only)
#define CH_SHORTS 24576

// ---------------------------------------------------------------------------
// Kernel 0: pack Wk [64,1024] fp32 -> BpkG [kc(32)][nt(4)][pl(2)][lane(64)][8]
// ---------------------------------------------------------------------------
__global__ __launch_bounds__(256) void prep_wk_kernel(const float* __restrict__ Wk,
                                                      short* __restrict__ BpkG) {
  int tg = blockIdx.x * 256 + threadIdx.x;  // 8192 = 32kc * 4nt * 64lane
  int kc = tg >> 8, rem = tg & 255, nt = rem >> 6, lane = rem & 63;
  int n = nt * 16 + (lane & 15);
  int k = kc * 32 + (lane >> 4) * 8;
  const float* src = Wk + (size_t)n * EMB + k;
  float4 a0 = *(const float4*)src;
  float4 a1 = *(const float4*)(src + 4);
  bf16x8 hi, lo;
  split_trunc(a0, a1, hi, lo);
  short* dst = BpkG + ((size_t)(kc * 4 + nt) * 128 + lane) * 8;  // pl=0
  *(bf16x8*)dst = hi;
  *(bf16x8*)(dst + 512) = lo;  // pl=1
}

// ---------------------------------------------------------------------------
// Kernel 1: K = emb @ Wk^T, LDS staging via global_load_lds.
// 512 blocks x 256; BM=16, K-loop 8 steps of BK=128.
// ---------------------------------------------------------------------------
__global__ __launch_bounds__(256) void gemm_k_kernel(const float* __restrict__ emb,
                                                     const short* __restrict__ BpkG,
                                                     short* __restrict__ Kpack) {
  __shared__ __align__(16) char glds[40960];
  float* embT = (float*)glds;             // [16][128] fp32, 16B-units XOR-swizzled by row
  short* bpkT = (short*)(glds + 8192);    // [kc(4)][nt(4)][pl(2)][lane][8]

  const int t = threadIdx.x;
  const int w = t >> 6, l = t & 63, lm = l & 15, quad = l >> 4;
  const int nt = w;
  const int row0 = blockIdx.x * 16;

  f32x4 acc = {0.f, 0.f, 0.f, 0.f};

  for (int step = 0; step < 8; ++step) {
    __syncthreads();  // previous-step LDS reads complete before overwrite
#pragma unroll
    for (int u = 0; u < 2; ++u) {
      int rowl = (w * 2 + u) * 2 + (l >> 5);
      int du = (l & 31) ^ (rowl & 7);
      async16(emb + (size_t)(row0 + rowl) * EMB + step * 128 + du * 4,
              embT + (w * 2 + u) * 256);
    }
    const short* bg = BpkG + (size_t)step * 16384;
#pragma unroll
    for (int u = 0; u < 8; ++u)
      async16(bg + (w * 8 + u) * 512 + l * 8, bpkT + (w * 8 + u) * 512);
    __syncthreads();  // drains vmcnt(0): all staging visible

#pragma unroll
    for (int kc = 0; kc < 4; ++kc) {
      int du0 = kc * 8 + quad * 2;
      float4 a0 = *(const float4*)((char*)embT + lm * 512 + ((du0) ^ (lm & 7)) * 16);
      float4 a1 = *(const float4*)((char*)embT + lm * 512 + ((du0 + 1) ^ (lm & 7)) * 16);
      bf16x8 ahi, alo;
      split_trunc(a0, a1, ahi, alo);
      bf16x8 bhi = *(const bf16x8*)(bpkT + (((kc * 4 + nt) * 2 + 0) * 64 + l) * 8);
      bf16x8 blo = *(const bf16x8*)(bpkT + (((kc * 4 + nt) * 2 + 1) * 64 + l) * 8);
      acc = MFMA16(ahi, bhi, acc);
      acc = MFMA16(ahi, blo, acc);
      acc = MFMA16(alo, bhi, acc);
    }
  }

  // epilogue: C layout (row=quad*4+r, col a=nt*16+lm) -> Kpack fragment scatter
  const int a = nt * 16 + lm;
#pragma unroll
  for (int r = 0; r < 4; ++r) {
    int srow = row0 + quad * 4 + r;
    float v = acc[r];
    short h = f2bf(v);
    short lo2 = f2bf(v - bf2f(h));
    int bb = srow >> 11, si = srow & 2047, c = si >> 7, key = si & 127;
    int kb = key >> 4, klm = key & 15;
    size_t cb = (size_t)(bb * 16 + c) * CH_SHORTS;
    size_t kbo = (size_t)((kb * 2 + (a >> 5)) * 64 + ((a & 31) >> 3) * 16 + klm) * 8 + (a & 7);
    Kpack[cb + kbo] = h;
    Kpack[cb + 8192 + kbo] = lo2;
    size_t vbo = (size_t)(((key >> 5) * 4 + (a >> 4)) * 64 + ((key & 31) >> 3) * 16 + (a & 15)) * 8 + (key & 7);
    Kpack[cb + 16384 + vbo] = h;
  }
}

// ---------------------------------------------------------------------------
// Kernel 2: flash partials. grid (16 chunks, 32 qt, 4 b) x 256.
// Whole 48 KB Kpack chunk staged via 12 async16/thread -> one barrier ->
// all fragment reads are ds_read_b128. Plds aliases dead KB region.
// ---------------------------------------------------------------------------
__global__ __launch_bounds__(256) void flash_kernel(const short* __restrict__ Kpack,
                                                    short* __restrict__ OpartH,
                                                    float2* __restrict__ mlpart) {
  const int chunk = blockIdx.x, qt = blockIdx.y, b = blockIdx.z;
  if (2 * chunk > qt) return;

  __shared__ __align__(16) short KLs[CH_SHORTS];
  const int t = threadIdx.x;
  const int w = t >> 6, l = t & 63, lm = l & 15, quad = l >> 4;
  const int qr0 = qt * 64 + w * 16, k0 = chunk * 128;

  // Q A-frags: 4 direct coalesced 16B loads from Kpack
  const short* qG = Kpack + (size_t)(b * 16 + (qt >> 1)) * CH_SHORTS + ((qt & 1) * 4 + w) * 1024;
  bf16x8 qh0 = *(const bf16x8*)(qG + l * 8);
  bf16x8 qh1 = *(const bf16x8*)(qG + 512 + l * 8);
  bf16x8 ql0 = *(const bf16x8*)(qG + 8192 + l * 8);
  bf16x8 ql1 = *(const bf16x8*)(qG + 8192 + 512 + l * 8);

  // stage the whole 48 KB chunk: 12 async issues per thread, zero VGPR
  const short* chunkG = Kpack + (size_t)(b * 16 + chunk) * CH_SHORTS;
#pragma unroll
  for (int u = 0; u < 12; ++u) {
    int slot = w * 12 + u;  // 48 slots x 1024 B
    async16(chunkG + slot * 512 + l * 8, KLs + slot * 512);
  }
  __syncthreads();  // vmcnt(0) drain: chunk resident in LDS

  // S = Q K^T: 8 key-groups x 2 a-chunks x split(hh+hl+lh)
  f32x4 sc[8];
#pragma unroll
  for (int g = 0; g < 8; ++g) {
    bf16x8 bh0 = *(const bf16x8*)(KLs + ((g * 2 + 0) * 64 + l) * 8);
    bf16x8 bh1 = *(const bf16x8*)(KLs + ((g * 2 + 1) * 64 + l) * 8);
    bf16x8 bl0 = *(const bf16x8*)(KLs + 8192 + ((g * 2 + 0) * 64 + l) * 8);
    bf16x8 bl1 = *(const bf16x8*)(KLs + 8192 + ((g * 2 + 1) * 64 + l) * 8);
    f32x4 s = {0.f, 0.f, 0.f, 0.f};
    s = MFMA16(qh0, bh0, s);
    s = MFMA16(qh0, bl0, s);
    s = MFMA16(ql0, bh0, s);
    s = MFMA16(qh1, bh1, s);
    s = MFMA16(qh1, bl1, s);
    s = MFMA16(ql1, bh1, s);
    sc[g] = s;
  }

  // mask + single-pass softmax (C layout: row=quad*4+r, col=g*16+lm)
  float rm[4] = {-INFINITY, -INFINITY, -INFINITY, -INFINITY};
#pragma unroll
  for (int g = 0; g < 8; ++g) {
    const int col = k0 + g * 16 + lm;
#pragma unroll
    for (int r = 0; r < 4; ++r) {
      const int row = qr0 + quad * 4 + r;
      float v = sc[g][r] * 0.125f;
      v = (col > row || v == 0.0f) ? -INFINITY : v;
      sc[g][r] = v;
      rm[r] = fmaxf(rm[r], v);
    }
  }
  float m_i[4], l_i[4];
#pragma unroll
  for (int r = 0; r < 4; ++r) {
    for (int off = 1; off < 16; off <<= 1) rm[r] = fmaxf(rm[r], __shfl_xor(rm[r], off, 16));
    m_i[r] = rm[r];
  }
  float rs[4] = {0.f, 0.f, 0.f, 0.f};
#pragma unroll
  for (int g = 0; g < 8; ++g)
#pragma unroll
    for (int r = 0; r < 4; ++r) {
      float p = (sc[g][r] == -INFINITY) ? 0.f : __expf(sc[g][r] - m_i[r]);
      sc[g][r] = p;
      rs[r] += p;
    }
#pragma unroll
  for (int r = 0; r < 4; ++r) {
    for (int off = 1; off < 16; off <<= 1) rs[r] += __shfl_xor(rs[r], off, 16);
    l_i[r] = rs[r];
  }

  __syncthreads();  // ALL waves done reading KBhi/KBlo -> safe to alias with Plds

  // P -> Plds (C layout -> A-operand layout), per-wave region in dead KB space
  short* Pw = KLs + w * 2112;  // [16][132] shorts
#pragma unroll
  for (int g = 0; g < 8; ++g)
#pragma unroll
    for (int r = 0; r < 4; ++r)
      Pw[(quad * 4 + r) * 132 + g * 16 + lm] = f2bf(sc[g][r]);

  // O = P V over 128 keys; V frags from VB region (disjoint from Plds)
  f32x4 o[4] = {{0.f,0.f,0.f,0.f},{0.f,0.f,0.f,0.f},{0.f,0.f,0.f,0.f},{0.f,0.f,0.f,0.f}};
#pragma unroll
  for (int kc2 = 0; kc2 < 4; ++kc2) {
    bf16x8 pf = *(const bf16x8*)(Pw + lm * 132 + kc2 * 32 + quad * 8);
#pragma unroll
    for (int nt = 0; nt < 4; ++nt) {
      bf16x8 vf = *(const bf16x8*)(KLs + 16384 + ((kc2 * 4 + nt) * 64 + l) * 8);
      o[nt] = MFMA16(pf, vf, o[nt]);
    }
  }

  // write partials: bf16 O (contiguous 8 KB/block) + packed (m,l)
  const int slot = b * 272 + slot_off(qt) + chunk;
  short* Ob = OpartH + (size_t)slot * 4096;
#pragma unroll
  for (int nt = 0; nt < 4; ++nt)
#pragma unroll
    for (int r = 0; r < 4; ++r)
      Ob[(size_t)(w * 16 + quad * 4 + r) * AH + nt * 16 + lm] = f2bf(o[nt][r]);
  if (lm == 0) {
#pragma unroll
    for (int r = 0; r < 4; ++r)
      mlpart[(size_t)slot * 64 + w * 16 + quad * 4 + r] = make_float2(m_i[r], l_i[r]);
  }
}

// ---------------------------------------------------------------------------
// Kernel 3 (REWRITTEN): merge via async LDS staging.
// grid (4 rowgroups, 32 qt, 4 b) = 512 blocks x 256.
// Stage <=16 chunk tiles [16 rows x 64 a] bf16 (<=32 KB) with zero-VGPR
// async16 (8 issues/thread), weights via in-wave shuffle-16 into LDS table,
// accumulate from LDS, float4-coalesced output. No serialized load chains.
// ---------------------------------------------------------------------------
__global__ __launch_bounds__(256) void merge_kernel(const short* __restrict__ OpartH,
                                                    const float2* __restrict__ mlpart,
                                                    float* __restrict__ out) {
  __shared__ __align__(16) short ldsO[16 * 1024];  // [chunk(16)][row(16)][a(64)] bf16
  __shared__ float wtab[16][17];                   // [row][chunk] weight/L
  const int t = threadIdx.x;
  const int w = t >> 6, l = t & 63;
  const int rg = blockIdx.x, qt = blockIdx.y, b = blockIdx.z;
  const int r0 = rg * 16;
  const int nch = (qt >> 1) + 1;
  const int slotbase = b * 272 + slot_off(qt);

  // stage Opart tiles: chunk c rows r0..r0+15 (2 KB) = 2 wave-issues each
#pragma unroll
  for (int u = 0; u < 8; ++u) {
    int idx = w * 8 + u;  // 32 issues x 1 KB
    int c = idx >> 1, half = idx & 1;
    if (c < nch)  // wave-uniform predicate
      async16(OpartH + (size_t)(slotbase + c) * 4096 + r0 * 64 + half * 512 + l * 8,
              ldsO + c * 1024 + half * 512 + l * 8);
  }

  // weights: wave w covers rows w*4..w*4+3; lane's chunk c = l&15
  const int row = w * 4 + (l >> 4), c = l & 15;
  float mc = -INFINITY, lc = 0.f;
  if (c < nch) {
    float2 ml = mlpart[(size_t)(slotbase + c) * 64 + r0 + row];
    mc = ml.x; lc = ml.y;
  }
  float M = mc;
  for (int off = 1; off < 16; off <<= 1) M = fmaxf(M, __shfl_xor(M, off, 16));
  float wgt = (mc != -INFINITY) ? __expf(mc - M) : 0.f;
  float L = lc * wgt;
  for (int off = 1; off < 16; off <<= 1) L += __shfl_xor(L, off, 16);
  wtab[row][c] = wgt / L;

  __syncthreads();  // drains async staging; wtab visible

  // accumulate: thread -> (row2 = t>>4, 4 cols at a0)
  const int row2 = t >> 4, a0 = (t & 15) * 4;
  float4 acc = make_float4(0.f, 0.f, 0.f, 0.f);
  for (int cc = 0; cc < nch; ++cc) {
    float wv = wtab[row2][cc];                       // broadcast read
    short4 v4 = *(const short4*)(ldsO + cc * 1024 + row2 * 64 + a0);
    acc.x += wv * bf2f(v4.x); acc.y += wv * bf2f(v4.y);
    acc.z += wv * bf2f(v4.z); acc.w += wv * bf2f(v4.w);
  }
  *(float4*)&out[((size_t)(b * 2048 + qt * 64 + r0 + row2)) * AH + a0] = acc;
}

// ---------------------------------------------------------------------------
// Workspace (bytes):
//   Kpack   [0,        3145728)    4 b x 16 chunks x 48 KB
//   BpkG    [3145728,  3670016)    256 KB (+slack)
//   OpartH  [3670016,  12582912)   1088 slots x 4096 bf16
//   mlpart  [12582912, 13139968)   1088 x 64 float2
// ---------------------------------------------------------------------------
extern "C" void kernel_launch(void* const* d_in, const int* in_sizes, int n_in,
                              void* d_out, int out_size, void* d_ws, size_t ws_size,
                              hipStream_t stream) {
  const float* emb = (const float*)d_in[0];
  const float* Wk  = (const float*)d_in[1];
  float* out = (float*)d_out;
  char* ws = (char*)d_ws;

  short*  Kpack  = (short*)(ws);
  short*  BpkG   = (short*)(ws + 3145728);
  short*  OpartH = (short*)(ws + 3670016);
  float2* mlpart = (float2*)(ws + 12582912);

  prep_wk_kernel<<<dim3(32), dim3(256), 0, stream>>>(Wk, BpkG);
  gemm_k_kernel<<<dim3(512), dim3(256), 0, stream>>>(emb, BpkG, Kpack);
  flash_kernel<<<dim3(16, 32, 4), dim3(256), 0, stream>>>(Kpack, OpartH, mlpart);
  merge_kernel<<<dim3(4, 32, 4), dim3(256), 0, stream>>>(OpartH, mlpart, out);
}